// Round 1
// baseline (390.020 us; speedup 1.0000x reference)
//
#include <hip/hip_runtime.h>
#include <math.h>

#define ALPHA_LEAKY 0.2f
#define EPS_F 1e-10f

__device__ __forceinline__ void atomicMaxFloat(float* addr, float val) {
    // Sign-split trick: for >=0, int compare matches float compare; for <0,
    // uint compare is reversed, so use atomicMin on the uint view.
    if (val >= 0.0f) {
        atomicMax((int*)addr, __float_as_int(val));
    } else {
        atomicMin((unsigned int*)addr, __float_as_uint(val));
    }
}

// Zero d_out and e_sum, set e_max = -inf (ws/out are poisoned 0xAA each call).
__global__ void k_init(float* __restrict__ out, float* __restrict__ e_max,
                       float* __restrict__ e_sum, int n_nodes, int total) {
    int i = blockIdx.x * blockDim.x + threadIdx.x;
    if (i < total) out[i] = 0.0f;
    if (i < n_nodes) {
        e_max[i] = -INFINITY;
        e_sum[i] = 0.0f;
    }
}

// h[n][o] = sum_k X[n][k] * W[o][k];  X:[N,128], W:[64,128], h:[N,64]
// Block = 256 threads, 32 rows per block. W staged in LDS with +1 pad
// (row stride 129) so lane-varying o reads hit banks (o+k)%32 -> conflict-free.
// X tile reads are wave-uniform (broadcast) -> no conflict, no pad needed.
__global__ __launch_bounds__(256) void k_linear(const float* __restrict__ X,
                                                const float* __restrict__ W,
                                                float* __restrict__ h, int n) {
    __shared__ float Wl[64 * 129];
    __shared__ float Xl[32 * 128];
    const int t = threadIdx.x;
    for (int i = t; i < 64 * 128; i += 256) {
        int r = i >> 7, c = i & 127;
        Wl[r * 129 + c] = W[i];
    }
    const int n0 = blockIdx.x * 32;
    for (int i = t; i < 32 * 128; i += 256) {
        int r = i >> 7, c = i & 127;
        int row = n0 + r;
        Xl[i] = (row < n) ? X[row * 128 + c] : 0.0f;
    }
    __syncthreads();

    const int o = t & 63;        // output dim (lane)
    const int rq = t >> 6;       // wave id -> row group
    float acc[8] = {0.f, 0.f, 0.f, 0.f, 0.f, 0.f, 0.f, 0.f};
    const float* xb = &Xl[rq * 8 * 128];
    const float* wb = &Wl[o * 129];
    for (int k = 0; k < 128; ++k) {
        float w = wb[k];
        #pragma unroll
        for (int j = 0; j < 8; ++j) acc[j] += xb[j * 128 + k] * w;
    }
    #pragma unroll
    for (int j = 0; j < 8; ++j) {
        int row = n0 + rq * 8 + j;
        if (row < n) h[row * 64 + o] = acc[j];
    }
}

// One wave per node: s_src[n] = h[n]·a[0:64], s_tgt[n] = h[n]·a[64:128]
__global__ __launch_bounds__(256) void k_scores(const float* __restrict__ h,
                                                const float* __restrict__ a,
                                                float* __restrict__ s_src,
                                                float* __restrict__ s_tgt, int n) {
    int t = threadIdx.x;
    int lane = t & 63;
    int node = blockIdx.x * 4 + (t >> 6);
    if (node >= n) return;
    float hv = h[node * 64 + lane];
    float p = hv * a[lane];
    float q = hv * a[64 + lane];
    #pragma unroll
    for (int off = 32; off > 0; off >>= 1) {
        p += __shfl_down(p, off, 64);
        q += __shfl_down(q, off, 64);
    }
    if (lane == 0) {
        s_src[node] = p;
        s_tgt[node] = q;
    }
}

// e = leaky_relu(s_src[src] + s_tgt[tgt]); store e; segment max into e_max[tgt]
__global__ void k_edge_max(const int* __restrict__ ei,
                           const float* __restrict__ s_src,
                           const float* __restrict__ s_tgt,
                           float* __restrict__ e_buf,
                           float* __restrict__ e_max, int E) {
    int e = blockIdx.x * blockDim.x + threadIdx.x;
    if (e >= E) return;
    int s = ei[e];
    int t = ei[E + e];
    float v = s_src[s] + s_tgt[t];
    v = (v > 0.0f) ? v : ALPHA_LEAKY * v;
    e_buf[e] = v;
    atomicMaxFloat(&e_max[t], v);
}

// e_exp = exp(e - e_max[tgt]); store in place; segment sum into e_sum[tgt]
__global__ void k_edge_exp(const int* __restrict__ ei,
                           const float* __restrict__ e_max,
                           float* __restrict__ e_buf,
                           float* __restrict__ e_sum, int E) {
    int e = blockIdx.x * blockDim.x + threadIdx.x;
    if (e >= E) return;
    int t = ei[E + e];
    float ex = expf(e_buf[e] - e_max[t]);
    e_buf[e] = ex;
    atomicAdd(&e_sum[t], ex);
}

// One thread per (edge, dim): out[tgt][d] += h[src][d] * e_exp/(e_sum[tgt]+eps)
// 64 lanes of a wave cover one edge: h-row read is one contiguous 256B gather,
// the e_buf/e_sum loads are wave-uniform broadcasts.
__global__ void k_aggregate(const int* __restrict__ ei,
                            const float* __restrict__ h,
                            const float* __restrict__ e_buf,
                            const float* __restrict__ e_sum,
                            float* __restrict__ out, int E) {
    int idx = blockIdx.x * blockDim.x + threadIdx.x;  // E*64 = 51.2M < 2^31
    if (idx >= E * 64) return;
    int e = idx >> 6;
    int d = idx & 63;
    int s = ei[e];
    int t = ei[E + e];
    float w = e_buf[e] / (e_sum[t] + EPS_F);
    atomicAdd(&out[t * 64 + d], h[s * 64 + d] * w);
}

__global__ void k_elu(float* __restrict__ out, int total) {
    int i = blockIdx.x * blockDim.x + threadIdx.x;
    if (i >= total) return;
    float x = out[i];
    out[i] = (x > 0.0f) ? x : (expf(x) - 1.0f);
}

extern "C" void kernel_launch(void* const* d_in, const int* in_sizes, int n_in,
                              void* d_out, int out_size, void* d_ws, size_t ws_size,
                              hipStream_t stream) {
    const float* X = (const float*)d_in[0];       // [N,128]
    const int*   ei = (const int*)d_in[1];        // [2,E] (src row, tgt row)
    const float* W = (const float*)d_in[2];       // [64,128]
    const float* a = (const float*)d_in[3];       // [1,128]
    float* out = (float*)d_out;                   // [N,64]

    const int N = in_sizes[0] / 128;              // 50000
    const int E = in_sizes[1] / 2;                // 800000

    float* ws = (float*)d_ws;
    float* h     = ws;                            // N*64
    float* s_src = h + (size_t)N * 64;            // N
    float* s_tgt = s_src + N;                     // N
    float* e_max = s_tgt + N;                     // N
    float* e_sum = e_max + N;                     // N
    float* e_buf = e_sum + N;                     // E (scores, then exp in place)

    const int total = N * 64;

    k_init<<<(total + 255) / 256, 256, 0, stream>>>(out, e_max, e_sum, N, total);
    k_linear<<<(N + 31) / 32, 256, 0, stream>>>(X, W, h, N);
    k_scores<<<(N + 3) / 4, 256, 0, stream>>>(h, a, s_src, s_tgt, N);
    k_edge_max<<<(E + 255) / 256, 256, 0, stream>>>(ei, s_src, s_tgt, e_buf, e_max, E);
    k_edge_exp<<<(E + 255) / 256, 256, 0, stream>>>(ei, e_max, e_buf, e_sum, E);
    const int agg_total = E * 64;
    k_aggregate<<<(agg_total + 255) / 256, 256, 0, stream>>>(ei, h, e_buf, e_sum, out, E);
    k_elu<<<(total + 255) / 256, 256, 0, stream>>>(out, total);
}

// Round 2
// 263.465 us; speedup vs baseline: 1.4804x; 1.4804x over previous
//
#include <hip/hip_runtime.h>
#include <math.h>

#define ALPHA_LEAKY 0.2f
#define EPS_F 1e-10f

// ---------------- fused linear + per-node scores ----------------
// h = X @ W^T  (X:[N,128], W:[64,128], h:[N,64])
// s_src[n] = h[n]·a[0:64], s_tgt[n] = h[n]·a[64:128]  (fused wave reduction)
// Block = 256 threads = 4 waves; 32 rows per block; lane = output dim.
// W staged in LDS with row stride 132 floats (528 B = 16B-aligned, and
// (4*o + k) % 32 bank pattern gives the minimal 8 words/bank for b128 reads).
// X tile reads are wave-uniform -> broadcast, no conflicts.
__global__ __launch_bounds__(256) void k_linear(const float* __restrict__ X,
                                                const float* __restrict__ W,
                                                const float* __restrict__ a,
                                                float* __restrict__ h,
                                                float* __restrict__ s_src,
                                                float* __restrict__ s_tgt, int n) {
    __shared__ float Wl[64 * 132];
    __shared__ float Xl[32 * 128];
    const int t = threadIdx.x;
    {
        const float4* W4 = (const float4*)W;
        for (int i = t; i < 64 * 32; i += 256) {
            int r = i >> 5, c = i & 31;
            *(float4*)&Wl[r * 132 + c * 4] = W4[i];
        }
    }
    const int n0 = blockIdx.x * 32;
    {
        const float4* X4 = (const float4*)X;
        for (int i = t; i < 32 * 32; i += 256) {
            int r = i >> 5, c = i & 31;
            int row = n0 + r;
            float4 v = make_float4(0.f, 0.f, 0.f, 0.f);
            if (row < n) v = X4[(size_t)row * 32 + c];
            *(float4*)&Xl[r * 128 + c * 4] = v;
        }
    }
    __syncthreads();

    const int o  = t & 63;   // output dim (lane)
    const int rq = t >> 6;   // wave id -> row group (8 rows each)
    float acc[8] = {0.f, 0.f, 0.f, 0.f, 0.f, 0.f, 0.f, 0.f};
    const float* xb = &Xl[rq * 8 * 128];
    const float* wb = &Wl[o * 132];
    for (int k0 = 0; k0 < 128; k0 += 4) {
        float4 wv = *(const float4*)&wb[k0];
        #pragma unroll
        for (int j = 0; j < 8; ++j) {
            float4 xv = *(const float4*)&xb[j * 128 + k0];
            acc[j] += xv.x * wv.x + xv.y * wv.y + xv.z * wv.z + xv.w * wv.w;
        }
    }
    const float a_s = a[o];
    const float a_t = a[64 + o];
    #pragma unroll
    for (int j = 0; j < 8; ++j) {
        int row = n0 + rq * 8 + j;
        if (row < n) h[(size_t)row * 64 + o] = acc[j];
        float p = acc[j] * a_s;
        float q = acc[j] * a_t;
        #pragma unroll
        for (int off = 32; off > 0; off >>= 1) {
            p += __shfl_xor(p, off, 64);
            q += __shfl_xor(q, off, 64);
        }
        if (o == 0 && row < n) { s_src[row] = p; s_tgt[row] = q; }
    }
}

// ---------------- CSR build ----------------
__global__ void k_count(const int* __restrict__ ei, int* __restrict__ deg, int E) {
    int e = blockIdx.x * blockDim.x + threadIdx.x;
    if (e < E) atomicAdd(&deg[ei[E + e]], 1);
}

// Assign each node a contiguous CSR segment. Segment placement is
// order-nondeterministic (one atomic per WAVE on a global cursor after an
// in-wave shfl prefix scan) but always contiguous & disjoint -> valid CSR.
__global__ void k_assign(const int* __restrict__ deg, int* __restrict__ gcur,
                         int* __restrict__ base, int* __restrict__ cursor, int n) {
    int i = blockIdx.x * blockDim.x + threadIdx.x;
    int lane = threadIdx.x & 63;
    int v = (i < n) ? deg[i] : 0;
    int pre = v;
    #pragma unroll
    for (int off = 1; off < 64; off <<= 1) {
        int tt = __shfl_up(pre, off, 64);
        if (lane >= off) pre += tt;
    }
    int total = __shfl(pre, 63, 64);
    int bw = 0;
    if (lane == 63) bw = atomicAdd(gcur, total);
    bw = __shfl(bw, 63, 64);
    int b = bw + pre - v;   // exclusive prefix within wave + wave base
    if (i < n) { base[i] = b; cursor[i] = b; }
}

// Scatter edges into CSR order; precompute leaky_relu score per edge.
__global__ void k_scatter(const int* __restrict__ ei,
                          const float* __restrict__ s_src,
                          const float* __restrict__ s_tgt,
                          int* __restrict__ cursor,
                          int* __restrict__ csr_src,
                          float* __restrict__ csr_v, int E) {
    int e = blockIdx.x * blockDim.x + threadIdx.x;
    if (e >= E) return;
    int s = ei[e];
    int t = ei[E + e];
    float v = s_src[s] + s_tgt[t];
    v = (v > 0.f) ? v : ALPHA_LEAKY * v;
    int pos = atomicAdd(&cursor[t], 1);
    csr_src[pos] = s;
    csr_v[pos] = v;
}

// ---------------- per-node softmax + aggregation + ELU ----------------
// One wave per node; lane = output dim. Segment max & exp-sum via shfl
// reductions; aggregation broadcasts (src, w) from each lane and does one
// coalesced 256 B h-row read + fma per edge. Single plain store per output.
__global__ __launch_bounds__(256) void k_node(const int* __restrict__ base,
                                              const int* __restrict__ deg,
                                              const int* __restrict__ csr_src,
                                              const float* __restrict__ csr_v,
                                              const float* __restrict__ h,
                                              float* __restrict__ out, int n) {
    const int lane = threadIdx.x & 63;
    const int node = blockIdx.x * 4 + (threadIdx.x >> 6);
    if (node >= n) return;
    const int b = base[node];
    const int d = deg[node];

    // pass 1: segment max
    float m = -INFINITY;
    for (int c = lane; c < d; c += 64) m = fmaxf(m, csr_v[b + c]);
    #pragma unroll
    for (int off = 32; off > 0; off >>= 1) m = fmaxf(m, __shfl_xor(m, off, 64));

    // pass 2: sum of exp
    float sum = 0.f;
    for (int c = lane; c < d; c += 64) sum += expf(csr_v[b + c] - m);
    #pragma unroll
    for (int off = 32; off > 0; off >>= 1) sum += __shfl_xor(sum, off, 64);
    const float inv = 1.f / (sum + EPS_F);

    // pass 3: weighted aggregation (lane j owns edge c0+j; broadcast to all)
    float acc = 0.f;
    for (int c0 = 0; c0 < d; c0 += 64) {
        int j = c0 + lane;
        int src = 0;
        float w = 0.f;
        if (j < d) {
            src = csr_src[b + j];
            w = expf(csr_v[b + j] - m) * inv;
        }
        int lim = min(64, d - c0);
        for (int k = 0; k < lim; ++k) {
            int s   = __shfl(src, k, 64);
            float wk = __shfl(w, k, 64);
            acc += wk * h[(size_t)s * 64 + lane];
        }
    }
    float r = acc > 0.f ? acc : expf(acc) - 1.f;   // fused ELU
    out[(size_t)node * 64 + lane] = r;
}

extern "C" void kernel_launch(void* const* d_in, const int* in_sizes, int n_in,
                              void* d_out, int out_size, void* d_ws, size_t ws_size,
                              hipStream_t stream) {
    const float* X  = (const float*)d_in[0];   // [N,128]
    const int*   ei = (const int*)d_in[1];     // [2,E]
    const float* W  = (const float*)d_in[2];   // [64,128]
    const float* a  = (const float*)d_in[3];   // [1,128]
    float* out = (float*)d_out;                // [N,64]

    const int N = in_sizes[0] / 128;
    const int E = in_sizes[1] / 2;

    char* p = (char*)d_ws;
    float* h      = (float*)p;  p += (size_t)N * 64 * sizeof(float);
    float* s_src  = (float*)p;  p += (size_t)N * sizeof(float);
    float* s_tgt  = (float*)p;  p += (size_t)N * sizeof(float);
    int*   deg    = (int*)p;    p += (size_t)N * sizeof(int);
    int*   gcur   = (int*)p;    p += sizeof(int);          // adjacent to deg
    int*   base   = (int*)p;    p += (size_t)N * sizeof(int);
    int*   cursor = (int*)p;    p += (size_t)N * sizeof(int);
    int*   csr_src= (int*)p;    p += (size_t)E * sizeof(int);
    float* csr_v  = (float*)p;

    // zero deg + gcur in one async memset (capturable)
    hipMemsetAsync(deg, 0, (size_t)(N + 1) * sizeof(int), stream);

    k_linear <<<(N + 31) / 32,  256, 0, stream>>>(X, W, a, h, s_src, s_tgt, N);
    k_count  <<<(E + 255) / 256, 256, 0, stream>>>(ei, deg, E);
    k_assign <<<(N + 255) / 256, 256, 0, stream>>>(deg, gcur, base, cursor, N);
    k_scatter<<<(E + 255) / 256, 256, 0, stream>>>(ei, s_src, s_tgt, cursor, csr_src, csr_v, E);
    k_node   <<<(N + 3) / 4,    256, 0, stream>>>(base, deg, csr_src, csr_v, h, out, N);
}

// Round 3
// 228.568 us; speedup vs baseline: 1.7064x; 1.1527x over previous
//
#include <hip/hip_runtime.h>
#include <math.h>

#define ALPHA_LEAKY 0.2f
#define EPS_F 1e-10f

// ---------------- fused: edge-degree count + linear + per-node scores -------
// Count slice first (independent of GEMM inputs; atomics retire underneath
// the GEMM). Then h = X @ W^T with fused s_src/s_tgt wave reductions.
__global__ __launch_bounds__(256) void k_linear_count(
    const float* __restrict__ X, const float* __restrict__ W,
    const float* __restrict__ a, const int* __restrict__ ei,
    float* __restrict__ h, float* __restrict__ s_src, float* __restrict__ s_tgt,
    int* __restrict__ deg, int n, int E, int epb) {
    const int t = threadIdx.x;

    // ---- degree count for this block's edge slice ----
    {
        int e0 = blockIdx.x * epb;
        int e1 = min(e0 + epb, E);
        for (int e = e0 + t; e < e1; e += 256)
            atomicAdd(&deg[ei[E + e]], 1);
    }

    // ---- GEMM: 32 rows per block ----
    __shared__ float Wl[64 * 132];   // +4 pad keeps b128 reads conflict-light
    __shared__ float Xl[32 * 128];
    {
        const float4* W4 = (const float4*)W;
        for (int i = t; i < 64 * 32; i += 256) {
            int r = i >> 5, c = i & 31;
            *(float4*)&Wl[r * 132 + c * 4] = W4[i];
        }
    }
    const int n0 = blockIdx.x * 32;
    {
        const float4* X4 = (const float4*)X;
        for (int i = t; i < 32 * 32; i += 256) {
            int r = i >> 5, c = i & 31;
            int row = n0 + r;
            float4 v = make_float4(0.f, 0.f, 0.f, 0.f);
            if (row < n) v = X4[(size_t)row * 32 + c];
            *(float4*)&Xl[r * 128 + c * 4] = v;
        }
    }
    __syncthreads();

    const int o  = t & 63;   // output dim (lane)
    const int rq = t >> 6;   // wave id -> row group (8 rows each)
    float acc[8] = {0.f, 0.f, 0.f, 0.f, 0.f, 0.f, 0.f, 0.f};
    const float* xb = &Xl[rq * 8 * 128];
    const float* wb = &Wl[o * 132];
    for (int k0 = 0; k0 < 128; k0 += 4) {
        float4 wv = *(const float4*)&wb[k0];
        #pragma unroll
        for (int j = 0; j < 8; ++j) {
            float4 xv = *(const float4*)&xb[j * 128 + k0];
            acc[j] += xv.x * wv.x + xv.y * wv.y + xv.z * wv.z + xv.w * wv.w;
        }
    }
    const float a_s = a[o];
    const float a_t = a[64 + o];
    #pragma unroll
    for (int j = 0; j < 8; ++j) {
        int row = n0 + rq * 8 + j;
        if (row < n) h[(size_t)row * 64 + o] = acc[j];
        float p = acc[j] * a_s;
        float q = acc[j] * a_t;
        #pragma unroll
        for (int off = 32; off > 0; off >>= 1) {
            p += __shfl_xor(p, off, 64);
            q += __shfl_xor(q, off, 64);
        }
        if (o == 0 && row < n) { s_src[row] = p; s_tgt[row] = q; }
    }
}

// ---------------- CSR segment assignment (scan over deg) ----------------
// Contiguous disjoint segments; placement order nondeterministic (valid CSR).
__global__ void k_assign(const int* __restrict__ deg, int* __restrict__ gcur,
                         int* __restrict__ base, int* __restrict__ cursor, int n) {
    int i = blockIdx.x * blockDim.x + threadIdx.x;
    int lane = threadIdx.x & 63;
    int v = (i < n) ? deg[i] : 0;
    int pre = v;
    #pragma unroll
    for (int off = 1; off < 64; off <<= 1) {
        int tt = __shfl_up(pre, off, 64);
        if (lane >= off) pre += tt;
    }
    int total = __shfl(pre, 63, 64);
    int bw = 0;
    if (lane == 63) bw = atomicAdd(gcur, total);
    bw = __shfl(bw, 63, 64);
    int b = bw + pre - v;
    if (i < n) { base[i] = b; cursor[i] = b; }
}

// ---------------- scatter: src index only (scores recomputed later) -------
__global__ void k_scatter(const int* __restrict__ ei, int* __restrict__ cursor,
                          int* __restrict__ csr_src, int E) {
    int e = blockIdx.x * blockDim.x + threadIdx.x;
    if (e >= E) return;
    int s = ei[e];
    int t = ei[E + e];
    int pos = atomicAdd(&cursor[t], 1);
    csr_src[pos] = s;
}

// ---------------- per-node softmax + aggregation + ELU ----------------
// One wave per node. Lane = (quarter q, sublane r): each k-step processes 4
// edges, each quarter reads one h row as float4 (4 independent dwordx4 rows
// in flight per wave instruction). d<=64 (virtually always, mean deg 16):
// per-edge data lives in registers, single csr gather.
__global__ __launch_bounds__(256) void k_node(
    const int* __restrict__ base, const int* __restrict__ deg,
    const int* __restrict__ csr_src, const float* __restrict__ s_src,
    const float* __restrict__ s_tgt, const float* __restrict__ h,
    float* __restrict__ out, int n) {
    const int lane = threadIdx.x & 63;
    const int node = blockIdx.x * 4 + (threadIdx.x >> 6);
    if (node >= n) return;
    const int b = base[node];
    const int d = deg[node];
    const float st = s_tgt[node];
    const float4* __restrict__ h4 = (const float4*)h;
    const int q = lane >> 4, r = lane & 15;
    float4 acc = make_float4(0.f, 0.f, 0.f, 0.f);

    if (d <= 64) {
        int src = 0; float v = -INFINITY;
        if (lane < d) {
            src = csr_src[b + lane];
            float x = s_src[src] + st;
            v = (x > 0.f) ? x : ALPHA_LEAKY * x;
        }
        float m = v;
        #pragma unroll
        for (int off = 32; off > 0; off >>= 1) m = fmaxf(m, __shfl_xor(m, off, 64));
        float ex = (lane < d) ? expf(v - m) : 0.f;
        float sum = ex;
        #pragma unroll
        for (int off = 32; off > 0; off >>= 1) sum += __shfl_xor(sum, off, 64);
        float w = ex * (1.f / (sum + EPS_F));
        // max k = largest mult of 4 < d <= 64  ->  ke = k+q <= 63: shfl in range
        for (int k = 0; k < d; k += 4) {
            int ke = k + q;
            int s    = __shfl(src, ke, 64);
            float wk = __shfl(w,  ke, 64);   // 0 for ke >= d
            float4 hv = h4[(size_t)s * 16 + r];
            acc.x += wk * hv.x; acc.y += wk * hv.y;
            acc.z += wk * hv.z; acc.w += wk * hv.w;
        }
    } else {  // rare general path (d > 64)
        float m = -INFINITY;
        for (int c = lane; c < d; c += 64) {
            float x = s_src[csr_src[b + c]] + st;
            x = (x > 0.f) ? x : ALPHA_LEAKY * x;
            m = fmaxf(m, x);
        }
        #pragma unroll
        for (int off = 32; off > 0; off >>= 1) m = fmaxf(m, __shfl_xor(m, off, 64));
        float sum = 0.f;
        for (int c = lane; c < d; c += 64) {
            float x = s_src[csr_src[b + c]] + st;
            x = (x > 0.f) ? x : ALPHA_LEAKY * x;
            sum += expf(x - m);
        }
        #pragma unroll
        for (int off = 32; off > 0; off >>= 1) sum += __shfl_xor(sum, off, 64);
        float inv = 1.f / (sum + EPS_F);
        for (int c0 = 0; c0 < d; c0 += 64) {
            int j = c0 + lane;
            int src = 0; float w = 0.f;
            if (j < d) {
                src = csr_src[b + j];
                float x = s_src[src] + st;
                x = (x > 0.f) ? x : ALPHA_LEAKY * x;
                w = expf(x - m) * inv;
            }
            int lim = min(64, d - c0);
            for (int k = 0; k < lim; k += 4) {
                int ke = k + q;
                int s    = __shfl(src, ke, 64);
                float wk = __shfl(w,  ke, 64);
                float4 hv = h4[(size_t)s * 16 + r];
                acc.x += wk * hv.x; acc.y += wk * hv.y;
                acc.z += wk * hv.z; acc.w += wk * hv.w;
            }
        }
    }

    // sum the 4 quarters (lanes r, r+16, r+32, r+48 hold dims 4r..4r+3)
    #pragma unroll
    for (int off = 32; off >= 16; off >>= 1) {
        acc.x += __shfl_xor(acc.x, off, 64);
        acc.y += __shfl_xor(acc.y, off, 64);
        acc.z += __shfl_xor(acc.z, off, 64);
        acc.w += __shfl_xor(acc.w, off, 64);
    }
    if (q == 0) {
        float4 o;
        o.x = acc.x > 0.f ? acc.x : expf(acc.x) - 1.f;
        o.y = acc.y > 0.f ? acc.y : expf(acc.y) - 1.f;
        o.z = acc.z > 0.f ? acc.z : expf(acc.z) - 1.f;
        o.w = acc.w > 0.f ? acc.w : expf(acc.w) - 1.f;
        ((float4*)out)[(size_t)node * 16 + r] = o;
    }
}

extern "C" void kernel_launch(void* const* d_in, const int* in_sizes, int n_in,
                              void* d_out, int out_size, void* d_ws, size_t ws_size,
                              hipStream_t stream) {
    const float* X  = (const float*)d_in[0];   // [N,128]
    const int*   ei = (const int*)d_in[1];     // [2,E]
    const float* W  = (const float*)d_in[2];   // [64,128]
    const float* a  = (const float*)d_in[3];   // [1,128]
    float* out = (float*)d_out;                // [N,64]

    const int N = in_sizes[0] / 128;
    const int E = in_sizes[1] / 2;

    char* p = (char*)d_ws;
    float* h      = (float*)p;  p += (size_t)N * 64 * sizeof(float);
    float* s_src  = (float*)p;  p += (size_t)N * sizeof(float);
    float* s_tgt  = (float*)p;  p += (size_t)N * sizeof(float);
    int*   deg    = (int*)p;    p += (size_t)N * sizeof(int);
    int*   gcur   = (int*)p;    p += sizeof(int);          // adjacent to deg
    int*   base   = (int*)p;    p += (size_t)N * sizeof(int);
    int*   cursor = (int*)p;    p += (size_t)N * sizeof(int);
    int*   csr_src= (int*)p;

    hipMemsetAsync(deg, 0, (size_t)(N + 1) * sizeof(int), stream);  // deg + gcur

    const int LB  = (N + 31) / 32;
    const int epb = (E + LB - 1) / LB;
    k_linear_count<<<LB, 256, 0, stream>>>(X, W, a, ei, h, s_src, s_tgt, deg, N, E, epb);
    k_assign <<<(N + 255) / 256, 256, 0, stream>>>(deg, gcur, base, cursor, N);
    k_scatter<<<(E + 255) / 256, 256, 0, stream>>>(ei, cursor, csr_src, E);
    k_node   <<<(N + 3) / 4,    256, 0, stream>>>(base, deg, csr_src, s_src, s_tgt, h, out, N);
}